// Round 16
// baseline (801.165 us; speedup 1.0000x reference)
//
#include <hip/hip_runtime.h>
#include <hip/hip_bf16.h>
#include <hip/hip_cooperative_groups.h>

namespace cg = cooperative_groups;

#define N_NODES 50000
#define N_EDGES 1600000
#define ET (N_EDGES + N_NODES)   // self-loops appended
#define IN_DIM 256
#define HID 128
#define NCLS 40
#define NEG 0.2f
#define NBUCK 391                // ceil(50000 / 128) buckets of 128 dst nodes
#define CHUNK 4096               // edges per binning task
#define CAP 5120                 // fixed bucket capacity (mean 4220, ~14 sigma headroom)
#define SCATB ((ET + CHUNK - 1) / CHUNK)   // 403 scatter tasks
#define GEMMB ((N_NODES + 63) / 64)        // 782 gemm0 tasks (64-node tiles)

typedef short bf16x8 __attribute__((ext_vector_type(8)));
typedef float f32x4  __attribute__((ext_vector_type(4)));

__device__ __forceinline__ unsigned pk2(float a, float b) {
    __hip_bfloat16 ha = __float2bfloat16(a), hb = __float2bfloat16(b);
    unsigned short ua = *(unsigned short*)&ha, ub = *(unsigned short*)&hb;
    return (unsigned)ua | ((unsigned)ub << 16);
}
__device__ __forceinline__ float blo(unsigned u) { return __uint_as_float(u << 16); }
__device__ __forceinline__ float bhi(unsigned u) { return __uint_as_float(u & 0xffff0000u); }

// One cooperative kernel; round-12 kernel bodies as phases with grid.sync().
__global__ __launch_bounds__(256, 4) void k_mega(
    const int* __restrict__ ei, int* __restrict__ cursor, unsigned int* __restrict__ buf,
    const float* __restrict__ x, const float* __restrict__ W0,
    const float* __restrict__ a_s0, const float* __restrict__ a_d0,
    unsigned short* __restrict__ h0b, float* __restrict__ as0, float* __restrict__ ad0,
    int* __restrict__ rp, int* __restrict__ re, int* __restrict__ csr,
    const float* __restrict__ b0, unsigned short* __restrict__ actb,
    const float* __restrict__ W1, const float* __restrict__ a_s1, const float* __restrict__ a_d1,
    unsigned short* __restrict__ h1b, float* __restrict__ as1, float* __restrict__ ad1,
    const float* __restrict__ b1, float* __restrict__ out) {
    __shared__ unsigned pool[6912];   // 27.6 KB (gemm0 phase is the max)
    cg::grid_group grid = cg::this_grid();
    const int t = threadIdx.x;
    const int nb = gridDim.x;

    // ================= Phase A: edge scatter ∥ gemm0 =================
    for (int task = blockIdx.x; task < SCATB + GEMMB; task += nb) {
        if (task < SCATB) {
            int* sd    = (int*)pool;            // [4096]
            int* hist  = (int*)pool + 4096;     // [391]
            int* wbase = (int*)pool + 4487;     // [391]
            for (int i = t; i < NBUCK; i += 256) hist[i] = 0;
            __syncthreads();
            int base = task * CHUNK;
            #pragma unroll
            for (int j = 0; j < 16; ++j) {
                int i = base + j * 256 + t;
                int d = -1;
                if (i < ET) d = (i < N_EDGES) ? ei[N_EDGES + i] : (i - N_EDGES);
                sd[j * 256 + t] = d;
                if (d >= 0) atomicAdd(&hist[d >> 7], 1);
            }
            __syncthreads();
            for (int i = t; i < NBUCK; i += 256) {
                int h = hist[i];
                wbase[i] = i * CAP + (h ? atomicAdd(&cursor[i], h) : 0);
                hist[i] = 0;              // reuse as running offset
            }
            __syncthreads();
            #pragma unroll
            for (int j = 0; j < 16; ++j) {
                int i = base + j * 256 + t;
                int d = sd[j * 256 + t];
                if (d >= 0) {
                    int s_ = (i < N_EDGES) ? ei[i] : d;
                    int bb = d >> 7;
                    int off = atomicAdd(&hist[bb], 1);
                    buf[wbase[bb] + off] = ((unsigned)(d & 127) << 16) | (unsigned)s_;
                }
            }
        } else {
            // gemm0: MFMA bf16, 64 nodes x 128 cols
            unsigned* sA = pool;              // bf16 [64 rows][72]
            unsigned* sB = pool + 2304;       // bf16 [128 cols][72]
            int n0 = (task - SCATB) * 64;
            int w = t >> 6, lane = t & 63;
            int rw = lane & 15, q = lane >> 4;
            f32x4 acc[8];
            #pragma unroll
            for (int n = 0; n < 8; ++n) acc[n] = (f32x4){0.f, 0.f, 0.f, 0.f};
            for (int kc = 0; kc < IN_DIM; kc += 64) {
                #pragma unroll
                for (int i = 0; i < 4; ++i) {
                    int f = i * 256 + t;
                    int r = f >> 4, fq = f & 15;
                    float4 v = make_float4(0.f, 0.f, 0.f, 0.f);
                    if (n0 + r < N_NODES)
                        v = *(const float4*)&x[(size_t)(n0 + r) * IN_DIM + kc + fq * 4];
                    *(uint2*)&sA[r * 36 + fq * 2] = make_uint2(pk2(v.x, v.y), pk2(v.z, v.w));
                }
                #pragma unroll
                for (int i = 0; i < 8; ++i) {
                    int f = i * 256 + t;
                    int c = f >> 4, fq = f & 15;
                    float4 v = *(const float4*)&W0[(size_t)c * IN_DIM + kc + fq * 4];
                    *(uint2*)&sB[c * 36 + fq * 2] = make_uint2(pk2(v.x, v.y), pk2(v.z, v.w));
                }
                __syncthreads();
                #pragma unroll
                for (int ks = 0; ks < 2; ++ks) {
                    bf16x8 af = *(const bf16x8*)((const unsigned short*)sA + (16 * w + rw) * 72 + ks * 32 + q * 8);
                    #pragma unroll
                    for (int n = 0; n < 8; ++n) {
                        bf16x8 bfr = *(const bf16x8*)((const unsigned short*)sB + (n * 16 + rw) * 72 + ks * 32 + q * 8);
                        acc[n] = __builtin_amdgcn_mfma_f32_16x16x32_bf16(af, bfr, acc[n], 0, 0, 0);
                    }
                }
                __syncthreads();
            }
            float asv[8], adv[8];
            #pragma unroll
            for (int n = 0; n < 8; ++n) { asv[n] = a_s0[n * 16 + rw]; adv[n] = a_d0[n * 16 + rw]; }
            float ps[4] = {0.f, 0.f, 0.f, 0.f}, pd[4] = {0.f, 0.f, 0.f, 0.f};
            #pragma unroll
            for (int n = 0; n < 8; ++n)
                #pragma unroll
                for (int reg = 0; reg < 4; ++reg) {
                    float vv = acc[n][reg];
                    ps[reg] += vv * asv[n];
                    pd[reg] += vv * adv[n];
                }
            #pragma unroll
            for (int reg = 0; reg < 4; ++reg) {
                int node = n0 + 16 * w + q * 4 + reg;
                if (node < N_NODES) {
                    #pragma unroll
                    for (int n = 0; n < 8; ++n) {
                        __hip_bfloat16 hb = __float2bfloat16(acc[n][reg]);
                        h0b[(size_t)node * HID + n * 16 + rw] = *(unsigned short*)&hb;
                    }
                }
            }
            #pragma unroll
            for (int reg = 0; reg < 4; ++reg)
                #pragma unroll
                for (int off = 1; off < 16; off <<= 1) {
                    ps[reg] += __shfl_xor(ps[reg], off);
                    pd[reg] += __shfl_xor(pd[reg], off);
                }
            if (rw == 0) {
                #pragma unroll
                for (int reg = 0; reg < 4; ++reg) {
                    int node = n0 + 16 * w + q * 4 + reg;
                    if (node < N_NODES) { as0[node] = ps[reg]; ad0[node] = pd[reg]; }
                }
            }
        }
        __syncthreads();
    }
    grid.sync();

    // ================= Phase B: bucket build (per-node CSR) =================
    for (int b = blockIdx.x; b < NBUCK; b += nb) {
        int* cnt = (int*)pool;
        int* rpl = (int*)pool + 128;
        int* cur = (int*)pool + 256;
        int lo = b * CAP, hi = lo + cursor[b];
        if (t < 128) cnt[t] = 0;
        __syncthreads();
        for (int i = lo + t; i < hi; i += 256) atomicAdd(&cnt[buf[i] >> 16], 1);
        __syncthreads();
        if (t == 0) {
            int run = 0;
            #pragma unroll
            for (int l = 0; l < 128; ++l) { rpl[l] = run; run += cnt[l]; }
        }
        __syncthreads();
        if (t < 128) {
            int node = b * 128 + t;
            if (node < N_NODES) { rp[node] = lo + rpl[t]; re[node] = lo + rpl[t] + cnt[t]; }
            cur[t] = 0;
        }
        __syncthreads();
        for (int i = lo + t; i < hi; i += 256) {
            unsigned v = buf[i];
            int dl = v >> 16;
            int off = atomicAdd(&cur[dl], 1);
            csr[lo + rpl[dl] + off] = (int)(v & 0xffffu);
        }
        __syncthreads();
    }
    grid.sync();

    // ================= Phase C: aggregation layer 0 =================
    {
        float* swp = (float*)pool;          // [4][64]
        int*   ssp = (int*)pool + 256;      // [4][64]
        const uint4* h0q = (const uint4*)h0b;
        int wid = t >> 6, lane = t & 63;
        int q = lane >> 4, ql = lane & 15;
        for (int g = blockIdx.x; g < N_NODES / 4; g += nb) {
            int node = g * 4 + wid;
            int start = rp[node], end = re[node];
            float ad_n = ad0[node];
            float a0 = 0.f, a1 = 0.f, a2 = 0.f, a3 = 0.f;
            float a4 = 0.f, a5 = 0.f, a6 = 0.f, a7 = 0.f, den = 0.f;
            for (int base = start; base < end; base += 64) {
                int mm = end - base; if (mm > 64) mm = 64;
                int s_l = 0; float w_l = 0.f;
                if (lane < mm) {
                    s_l = csr[base + lane];
                    float e = as0[s_l] + ad_n;
                    e = (e > 0.f) ? e : NEG * e;
                    w_l = __expf(e);
                    den += w_l;
                }
                ssp[wid * 64 + lane] = s_l;   // slots >= mm: s=0, w=0 -> contribute 0
                swp[wid * 64 + lane] = w_l;   // wave-local: no barrier needed
                for (int jj = 0; jj < mm; jj += 16) {
                    int i0 = jj + q, i1 = i0 + 4, i2 = i0 + 8, i3 = i0 + 12;
                    int   s0 = ssp[wid * 64 + i0], s1 = ssp[wid * 64 + i1];
                    int   s2 = ssp[wid * 64 + i2], s3 = ssp[wid * 64 + i3];
                    float w0 = swp[wid * 64 + i0], w1 = swp[wid * 64 + i1];
                    float w2 = swp[wid * 64 + i2], w3 = swp[wid * 64 + i3];
                    uint4 u0 = h0q[(size_t)s0 * 16 + ql];
                    uint4 u1 = h0q[(size_t)s1 * 16 + ql];
                    uint4 u2 = h0q[(size_t)s2 * 16 + ql];
                    uint4 u3 = h0q[(size_t)s3 * 16 + ql];
                    a0 += w0 * blo(u0.x) + w1 * blo(u1.x) + w2 * blo(u2.x) + w3 * blo(u3.x);
                    a1 += w0 * bhi(u0.x) + w1 * bhi(u1.x) + w2 * bhi(u2.x) + w3 * bhi(u3.x);
                    a2 += w0 * blo(u0.y) + w1 * blo(u1.y) + w2 * blo(u2.y) + w3 * blo(u3.y);
                    a3 += w0 * bhi(u0.y) + w1 * bhi(u1.y) + w2 * bhi(u2.y) + w3 * bhi(u3.y);
                    a4 += w0 * blo(u0.z) + w1 * blo(u1.z) + w2 * blo(u2.z) + w3 * blo(u3.z);
                    a5 += w0 * bhi(u0.z) + w1 * bhi(u1.z) + w2 * bhi(u2.z) + w3 * bhi(u3.z);
                    a6 += w0 * blo(u0.w) + w1 * blo(u1.w) + w2 * blo(u2.w) + w3 * blo(u3.w);
                    a7 += w0 * bhi(u0.w) + w1 * bhi(u1.w) + w2 * bhi(u2.w) + w3 * bhi(u3.w);
                }
            }
            #pragma unroll
            for (int off = 32; off; off >>= 1) den += __shfl_xor(den, off);
            a0 += __shfl_xor(a0, 16); a0 += __shfl_xor(a0, 32);
            a1 += __shfl_xor(a1, 16); a1 += __shfl_xor(a1, 32);
            a2 += __shfl_xor(a2, 16); a2 += __shfl_xor(a2, 32);
            a3 += __shfl_xor(a3, 16); a3 += __shfl_xor(a3, 32);
            a4 += __shfl_xor(a4, 16); a4 += __shfl_xor(a4, 32);
            a5 += __shfl_xor(a5, 16); a5 += __shfl_xor(a5, 32);
            a6 += __shfl_xor(a6, 16); a6 += __shfl_xor(a6, 32);
            a7 += __shfl_xor(a7, 16); a7 += __shfl_xor(a7, 32);
            if (lane < 16) {
                float inv = 1.f / fmaxf(den, 1e-16f);
                float4 b0v = *(const float4*)&b0[ql * 8];
                float4 b1v = *(const float4*)&b0[ql * 8 + 4];
                float r0 = fmaxf(a0 * inv + b0v.x, 0.f);
                float r1 = fmaxf(a1 * inv + b0v.y, 0.f);
                float r2 = fmaxf(a2 * inv + b0v.z, 0.f);
                float r3 = fmaxf(a3 * inv + b0v.w, 0.f);
                float r4 = fmaxf(a4 * inv + b1v.x, 0.f);
                float r5 = fmaxf(a5 * inv + b1v.y, 0.f);
                float r6 = fmaxf(a6 * inv + b1v.z, 0.f);
                float r7 = fmaxf(a7 * inv + b1v.w, 0.f);
                *(uint4*)&actb[(size_t)node * HID + ql * 8] =
                    make_uint4(pk2(r0, r1), pk2(r2, r3), pk2(r4, r5), pk2(r6, r7));
            }
        }
    }
    grid.sync();

    // ================= Phase D: gemm1 (h1 = act @ W1^T + alpha dots) =========
    {
        float* w1l = (float*)pool;          // [40*128]
        float* av  = (float*)pool + 5120;   // [40]
        float* adv = (float*)pool + 5160;   // [40]
        #pragma unroll
        for (int i = 0; i < 5; ++i) {
            int j = t + 256 * i;
            ((float4*)w1l)[j] = ((const float4*)W1)[j];
        }
        if (t < NCLS) { av[t] = a_s1[t]; adv[t] = a_d1[t]; }
        __syncthreads();
        for (int g = blockIdx.x; g < (N_NODES + 255) / 256; g += nb) {
            int n = g * 256 + t;
            if (n < N_NODES) {
                const uint4* ar = (const uint4*)(actb + (size_t)n * HID);
                float acc[NCLS];
                #pragma unroll
                for (int c = 0; c < NCLS; ++c) acc[c] = 0.f;
                for (int k0 = 0; k0 < HID; k0 += 8) {
                    uint4 v = ar[k0 >> 3];
                    float x0 = blo(v.x), x1 = bhi(v.x), x2 = blo(v.y), x3 = bhi(v.y);
                    float x4 = blo(v.z), x5 = bhi(v.z), x6 = blo(v.w), x7 = bhi(v.w);
                    #pragma unroll
                    for (int c = 0; c < NCLS; ++c) {
                        const float* wr = &w1l[c * HID + k0];
                        acc[c] += x0 * wr[0] + x1 * wr[1] + x2 * wr[2] + x3 * wr[3]
                                + x4 * wr[4] + x5 * wr[5] + x6 * wr[6] + x7 * wr[7];
                    }
                }
                float ps = 0.f, pd = 0.f;
                #pragma unroll
                for (int c = 0; c < NCLS; ++c) { ps += acc[c] * av[c]; pd += acc[c] * adv[c]; }
                unsigned pk_[20];
                #pragma unroll
                for (int c = 0; c < 20; ++c) pk_[c] = pk2(acc[2 * c], acc[2 * c + 1]);
                #pragma unroll
                for (int i = 0; i < 5; ++i)
                    *(uint4*)&h1b[(size_t)n * NCLS + i * 8] =
                        make_uint4(pk_[4*i], pk_[4*i+1], pk_[4*i+2], pk_[4*i+3]);
                as1[n] = ps; ad1[n] = pd;
            }
        }
    }
    grid.sync();

    // ================= Phase E: aggregation layer 1 -> out =================
    {
        float* swp = (float*)pool;
        int*   ssp = (int*)pool + 256;
        const uint2* h1u = (const uint2*)h1b;
        int wid = t >> 6, lane = t & 63;
        int q = lane >> 4, ql = lane & 15;
        int off10 = (ql < 10) ? ql : 0;
        for (int g = blockIdx.x; g < N_NODES / 4; g += nb) {
            int node = g * 4 + wid;
            int start = rp[node], end = re[node];
            float ad_n = ad1[node];
            float a0 = 0.f, a1 = 0.f, a2 = 0.f, a3 = 0.f, den = 0.f;
            for (int base = start; base < end; base += 64) {
                int mm = end - base; if (mm > 64) mm = 64;
                int s_l = 0; float w_l = 0.f;
                if (lane < mm) {
                    s_l = csr[base + lane];
                    float e = as1[s_l] + ad_n;
                    e = (e > 0.f) ? e : NEG * e;
                    w_l = __expf(e);
                    den += w_l;
                }
                ssp[wid * 64 + lane] = s_l;
                swp[wid * 64 + lane] = w_l;
                for (int jj = 0; jj < mm; jj += 16) {
                    int i0 = jj + q, i1 = i0 + 4, i2 = i0 + 8, i3 = i0 + 12;
                    int   s0 = ssp[wid * 64 + i0], s1 = ssp[wid * 64 + i1];
                    int   s2 = ssp[wid * 64 + i2], s3 = ssp[wid * 64 + i3];
                    float w0 = swp[wid * 64 + i0], w1 = swp[wid * 64 + i1];
                    float w2 = swp[wid * 64 + i2], w3 = swp[wid * 64 + i3];
                    uint2 u0 = h1u[(size_t)s0 * 10 + off10];
                    uint2 u1 = h1u[(size_t)s1 * 10 + off10];
                    uint2 u2 = h1u[(size_t)s2 * 10 + off10];
                    uint2 u3 = h1u[(size_t)s3 * 10 + off10];
                    a0 += w0 * blo(u0.x) + w1 * blo(u1.x) + w2 * blo(u2.x) + w3 * blo(u3.x);
                    a1 += w0 * bhi(u0.x) + w1 * bhi(u1.x) + w2 * bhi(u2.x) + w3 * bhi(u3.x);
                    a2 += w0 * blo(u0.y) + w1 * blo(u1.y) + w2 * blo(u2.y) + w3 * blo(u3.y);
                    a3 += w0 * bhi(u0.y) + w1 * bhi(u1.y) + w2 * bhi(u2.y) + w3 * bhi(u3.y);
                }
            }
            #pragma unroll
            for (int off = 32; off; off >>= 1) den += __shfl_xor(den, off);
            a0 += __shfl_xor(a0, 16); a0 += __shfl_xor(a0, 32);
            a1 += __shfl_xor(a1, 16); a1 += __shfl_xor(a1, 32);
            a2 += __shfl_xor(a2, 16); a2 += __shfl_xor(a2, 32);
            a3 += __shfl_xor(a3, 16); a3 += __shfl_xor(a3, 32);
            if (lane < 10) {
                float inv = 1.f / fmaxf(den, 1e-16f);
                float4 b4 = *(const float4*)&b1[ql * 4];
                float4 r;
                r.x = a0 * inv + b4.x;
                r.y = a1 * inv + b4.y;
                r.z = a2 * inv + b4.z;
                r.w = a3 * inv + b4.w;
                *(float4*)&out[(size_t)node * NCLS + ql * 4] = r;
            }
        }
    }
}

extern "C" void kernel_launch(void* const* d_in, const int* in_sizes, int n_in,
                              void* d_out, int out_size, void* d_ws, size_t ws_size,
                              hipStream_t stream) {
    const float* x    = (const float*)d_in[0];
    const int*   ei   = (const int*)d_in[1];
    const float* W0   = (const float*)d_in[2];
    const float* a_s0 = (const float*)d_in[3];
    const float* a_d0 = (const float*)d_in[4];
    const float* b0   = (const float*)d_in[5];
    const float* W1   = (const float*)d_in[6];
    const float* a_s1 = (const float*)d_in[7];
    const float* a_d1 = (const float*)d_in[8];
    const float* b1   = (const float*)d_in[9];

    char* p = (char*)d_ws;
    auto alloc = [&](size_t bytes) { void* q = p; p += (bytes + 255) & ~size_t(255); return q; };
    unsigned short* h0b  = (unsigned short*)alloc((size_t)N_NODES * HID * 2);  // 12.8MB bf16
    unsigned int*   buf  = (unsigned int*)alloc((size_t)NBUCK * CAP * 4);      // 8.0MB
    int*   csr    = (int*)alloc((size_t)NBUCK * CAP * 4);                      // 8.0MB bucket-major
    unsigned short* h1b  = (unsigned short*)alloc(((size_t)N_NODES * NCLS + 32) * 2);
    unsigned short* actb = (unsigned short*)alloc((size_t)N_NODES * HID * 2);  // bf16
    float* as0    = (float*)alloc((size_t)N_NODES * 4);
    float* ad0    = (float*)alloc((size_t)N_NODES * 4);
    float* as1    = (float*)alloc((size_t)N_NODES * 4);
    float* ad1    = (float*)alloc((size_t)N_NODES * 4);
    int*   rp     = (int*)alloc((size_t)N_NODES * 4);
    int*   re     = (int*)alloc((size_t)N_NODES * 4);
    int*   cursor = (int*)alloc((size_t)NBUCK * 4);
    float* outp   = (float*)d_out;

    hipMemsetAsync(cursor, 0, (size_t)NBUCK * 4, stream);

    int mpc = 0;
    hipOccupancyMaxActiveBlocksPerMultiprocessor(&mpc, (const void*)k_mega, 256, 0);
    if (mpc < 1) mpc = 1;
    long long grid = (long long)mpc * 256;   // 256 CUs
    if (grid > 2048) grid = 2048;

    void* args[] = { (void*)&ei, (void*)&cursor, (void*)&buf,
                     (void*)&x, (void*)&W0, (void*)&a_s0, (void*)&a_d0,
                     (void*)&h0b, (void*)&as0, (void*)&ad0,
                     (void*)&rp, (void*)&re, (void*)&csr,
                     (void*)&b0, (void*)&actb,
                     (void*)&W1, (void*)&a_s1, (void*)&a_d1,
                     (void*)&h1b, (void*)&as1, (void*)&ad1,
                     (void*)&b1, (void*)&outp };
    hipLaunchCooperativeKernel((const void*)k_mega, dim3((unsigned)grid), dim3(256),
                               args, 0, stream);
}

// Round 17
// 269.363 us; speedup vs baseline: 2.9743x; 2.9743x over previous
//
#include <hip/hip_runtime.h>
#include <hip/hip_bf16.h>

#define N_NODES 50000
#define N_EDGES 1600000
#define ET (N_EDGES + N_NODES)   // self-loops appended
#define IN_DIM 256
#define HID 128
#define NCLS 40
#define NEG 0.2f
#define NBUCK 391                // ceil(50000 / 128) buckets of 128 dst nodes
#define CHUNK 8192               // edges per binning task (no LDS staging needed)
#define CAP 5120                 // fixed bucket capacity (mean 4220, ~14 sigma headroom)
#define SCATB ((ET + CHUNK - 1) / CHUNK)   // 202 scatter tasks
#define GEMMB ((N_NODES + 63) / 64)        // 782 gemm0 tasks (64-node tiles)

typedef short bf16x8 __attribute__((ext_vector_type(8)));
typedef float f32x4  __attribute__((ext_vector_type(4)));

__device__ __forceinline__ unsigned pk2(float a, float b) {
    __hip_bfloat16 ha = __float2bfloat16(a), hb = __float2bfloat16(b);
    unsigned short ua = *(unsigned short*)&ha, ub = *(unsigned short*)&hb;
    return (unsigned)ua | ((unsigned)ub << 16);
}
__device__ __forceinline__ float blo(unsigned u) { return __uint_as_float(u << 16); }
__device__ __forceinline__ float bhi(unsigned u) { return __uint_as_float(u & 0xffff0000u); }

// ---------------- Fused: edge binning (blocks 0..SCATB) ∥ gemm0 64-tile --------
// cursor[] zero-initialized by hipMemsetAsync; bucket-relative offsets.
// Scatter re-reads ei in pass 2 (L2-hot) instead of staging dst in LDS.
__global__ __launch_bounds__(256) void k_fused(
    const int* __restrict__ ei, int* __restrict__ cursor, unsigned int* __restrict__ buf,
    const float* __restrict__ x, const float* __restrict__ W0,
    const float* __restrict__ a_s, const float* __restrict__ a_d,
    unsigned short* __restrict__ h0b, float* __restrict__ as0, float* __restrict__ ad0) {
    __shared__ unsigned pool[6912];   // 27.6 KB (gemm0 path is the max)
    int t = threadIdx.x;

    if (blockIdx.x < SCATB) {
        int* hist  = (int*)pool;            // [391]
        int* wbase = (int*)pool + 391;      // [391]
        for (int i = t; i < NBUCK; i += 256) hist[i] = 0;
        __syncthreads();
        int base = blockIdx.x * CHUNK;
        #pragma unroll
        for (int j = 0; j < 32; ++j) {
            int i = base + j * 256 + t;
            if (i < ET) {
                int d = (i < N_EDGES) ? ei[N_EDGES + i] : (i - N_EDGES);
                atomicAdd(&hist[d >> 7], 1);
            }
        }
        __syncthreads();
        for (int i = t; i < NBUCK; i += 256) {
            int h = hist[i];
            wbase[i] = i * CAP + (h ? atomicAdd(&cursor[i], h) : 0);
            hist[i] = 0;              // reuse as running offset
        }
        __syncthreads();
        #pragma unroll
        for (int j = 0; j < 32; ++j) {
            int i = base + j * 256 + t;
            if (i < ET) {
                int d, s_;
                if (i < N_EDGES) { d = ei[N_EDGES + i]; s_ = ei[i]; }
                else             { d = s_ = i - N_EDGES; }
                int b = d >> 7;
                int off = atomicAdd(&hist[b], 1);
                buf[wbase[b] + off] = ((unsigned)(d & 127) << 16) | (unsigned)s_;
            }
        }
        return;
    }

    // ---- gemm0: MFMA bf16, 64 nodes x 128 cols per block (round-12 proven) ----
    unsigned* sA = pool;              // bf16 [64 rows][72]
    unsigned* sB = pool + 2304;       // bf16 [128 cols][72]
    int n0 = (blockIdx.x - SCATB) * 64;
    int w = t >> 6, lane = t & 63;
    int rw = lane & 15, q = lane >> 4;
    f32x4 acc[8];
    #pragma unroll
    for (int n = 0; n < 8; ++n) acc[n] = (f32x4){0.f, 0.f, 0.f, 0.f};

    for (int kc = 0; kc < IN_DIM; kc += 64) {
        #pragma unroll
        for (int i = 0; i < 4; ++i) {
            int f = i * 256 + t;
            int r = f >> 4, fq = f & 15;
            float4 v = make_float4(0.f, 0.f, 0.f, 0.f);
            if (n0 + r < N_NODES)
                v = *(const float4*)&x[(size_t)(n0 + r) * IN_DIM + kc + fq * 4];
            *(uint2*)&sA[r * 36 + fq * 2] = make_uint2(pk2(v.x, v.y), pk2(v.z, v.w));
        }
        #pragma unroll
        for (int i = 0; i < 8; ++i) {
            int f = i * 256 + t;
            int c = f >> 4, fq = f & 15;
            float4 v = *(const float4*)&W0[(size_t)c * IN_DIM + kc + fq * 4];
            *(uint2*)&sB[c * 36 + fq * 2] = make_uint2(pk2(v.x, v.y), pk2(v.z, v.w));
        }
        __syncthreads();
        #pragma unroll
        for (int ks = 0; ks < 2; ++ks) {
            bf16x8 af = *(const bf16x8*)((const unsigned short*)sA + (16 * w + rw) * 72 + ks * 32 + q * 8);
            #pragma unroll
            for (int n = 0; n < 8; ++n) {
                bf16x8 bfr = *(const bf16x8*)((const unsigned short*)sB + (n * 16 + rw) * 72 + ks * 32 + q * 8);
                acc[n] = __builtin_amdgcn_mfma_f32_16x16x32_bf16(af, bfr, acc[n], 0, 0, 0);
            }
        }
        __syncthreads();
    }

    float asv[8], adv[8];
    #pragma unroll
    for (int n = 0; n < 8; ++n) { asv[n] = a_s[n * 16 + rw]; adv[n] = a_d[n * 16 + rw]; }
    float ps[4] = {0.f, 0.f, 0.f, 0.f}, pd[4] = {0.f, 0.f, 0.f, 0.f};
    #pragma unroll
    for (int n = 0; n < 8; ++n)
        #pragma unroll
        for (int reg = 0; reg < 4; ++reg) {
            float vv = acc[n][reg];
            ps[reg] += vv * asv[n];
            pd[reg] += vv * adv[n];
        }
    #pragma unroll
    for (int reg = 0; reg < 4; ++reg) {
        int node = n0 + 16 * w + q * 4 + reg;
        if (node < N_NODES) {
            #pragma unroll
            for (int n = 0; n < 8; ++n) {
                __hip_bfloat16 hb = __float2bfloat16(acc[n][reg]);
                h0b[(size_t)node * HID + n * 16 + rw] = *(unsigned short*)&hb;
            }
        }
    }
    #pragma unroll
    for (int reg = 0; reg < 4; ++reg)
        #pragma unroll
        for (int off = 1; off < 16; off <<= 1) {
            ps[reg] += __shfl_xor(ps[reg], off);
            pd[reg] += __shfl_xor(pd[reg], off);
        }
    if (rw == 0) {
        #pragma unroll
        for (int reg = 0; reg < 4; ++reg) {
            int node = n0 + 16 * w + q * 4 + reg;
            if (node < N_NODES) { as0[node] = ps[reg]; ad0[node] = pd[reg]; }
        }
    }
}

// ---------------- Bucket build: per-node CSR within fixed-CAP layout -----------
__global__ __launch_bounds__(512) void k_bucket_build(const unsigned int* __restrict__ buf,
                                                      const int* __restrict__ cursor,
                                                      int* __restrict__ rp, int* __restrict__ re,
                                                      int* __restrict__ csr) {
    __shared__ int cnt[128], rpl[128], cur[128];
    int b = blockIdx.x;
    int t = threadIdx.x;
    int lo = b * CAP, hi = lo + cursor[b];
    if (t < 128) cnt[t] = 0;
    __syncthreads();
    for (int i = lo + t; i < hi; i += 512) atomicAdd(&cnt[buf[i] >> 16], 1);
    __syncthreads();
    if (t == 0) {
        int run = 0;
        #pragma unroll
        for (int l = 0; l < 128; ++l) { rpl[l] = run; run += cnt[l]; }
    }
    __syncthreads();
    if (t < 128) {
        int node = b * 128 + t;
        if (node < N_NODES) { rp[node] = lo + rpl[t]; re[node] = lo + rpl[t] + cnt[t]; }
        cur[t] = 0;
    }
    __syncthreads();
    for (int i = lo + t; i < hi; i += 512) {
        unsigned v = buf[i];
        int dl = v >> 16;
        int off = atomicAdd(&cur[dl], 1);
        csr[lo + rpl[dl] + off] = (int)(v & 0xffffu);
    }
}

// ---------------- Aggregation layer 0 (bf16 h0): wave/node, quarter-wave rows --
__global__ __launch_bounds__(256) void k_agg0(
    const uint4* __restrict__ h0q, const float* __restrict__ as, const float* __restrict__ ad,
    const int* __restrict__ rp, const int* __restrict__ re, const int* __restrict__ csr,
    const float* __restrict__ bias, unsigned short* __restrict__ actb) {
    __shared__ float sw_[4][64];
    __shared__ int   ss_[4][64];
    int wid = threadIdx.x >> 6, lane = threadIdx.x & 63;
    int q = lane >> 4, ql = lane & 15;
    int node = blockIdx.x * 4 + wid;
    int start = rp[node], end = re[node];
    float ad_n = ad[node];
    float a0 = 0.f, a1 = 0.f, a2 = 0.f, a3 = 0.f;
    float a4 = 0.f, a5 = 0.f, a6 = 0.f, a7 = 0.f, den = 0.f;
    for (int base = start; base < end; base += 64) {
        int mm = end - base; if (mm > 64) mm = 64;
        int s_l = 0; float w_l = 0.f;
        if (lane < mm) {
            s_l = csr[base + lane];
            float e = as[s_l] + ad_n;
            e = (e > 0.f) ? e : NEG * e;
            w_l = __expf(e);
            den += w_l;
        }
        ss_[wid][lane] = s_l;      // slots >= mm: s=0, w=0 -> contribute 0
        sw_[wid][lane] = w_l;      // wave-local LDS: no barrier needed
        for (int jj = 0; jj < mm; jj += 16) {
            int i0 = jj + q, i1 = i0 + 4, i2 = i0 + 8, i3 = i0 + 12;
            int   s0 = ss_[wid][i0], s1 = ss_[wid][i1], s2 = ss_[wid][i2], s3 = ss_[wid][i3];
            float w0 = sw_[wid][i0], w1 = sw_[wid][i1], w2 = sw_[wid][i2], w3 = sw_[wid][i3];
            uint4 u0 = h0q[(size_t)s0 * 16 + ql];
            uint4 u1 = h0q[(size_t)s1 * 16 + ql];
            uint4 u2 = h0q[(size_t)s2 * 16 + ql];
            uint4 u3 = h0q[(size_t)s3 * 16 + ql];
            a0 += w0 * blo(u0.x) + w1 * blo(u1.x) + w2 * blo(u2.x) + w3 * blo(u3.x);
            a1 += w0 * bhi(u0.x) + w1 * bhi(u1.x) + w2 * bhi(u2.x) + w3 * bhi(u3.x);
            a2 += w0 * blo(u0.y) + w1 * blo(u1.y) + w2 * blo(u2.y) + w3 * blo(u3.y);
            a3 += w0 * bhi(u0.y) + w1 * bhi(u1.y) + w2 * bhi(u2.y) + w3 * bhi(u3.y);
            a4 += w0 * blo(u0.z) + w1 * blo(u1.z) + w2 * blo(u2.z) + w3 * blo(u3.z);
            a5 += w0 * bhi(u0.z) + w1 * bhi(u1.z) + w2 * bhi(u2.z) + w3 * bhi(u3.z);
            a6 += w0 * blo(u0.w) + w1 * blo(u1.w) + w2 * blo(u2.w) + w3 * blo(u3.w);
            a7 += w0 * bhi(u0.w) + w1 * bhi(u1.w) + w2 * bhi(u2.w) + w3 * bhi(u3.w);
        }
    }
    #pragma unroll
    for (int off = 32; off; off >>= 1) den += __shfl_xor(den, off);
    a0 += __shfl_xor(a0, 16); a0 += __shfl_xor(a0, 32);
    a1 += __shfl_xor(a1, 16); a1 += __shfl_xor(a1, 32);
    a2 += __shfl_xor(a2, 16); a2 += __shfl_xor(a2, 32);
    a3 += __shfl_xor(a3, 16); a3 += __shfl_xor(a3, 32);
    a4 += __shfl_xor(a4, 16); a4 += __shfl_xor(a4, 32);
    a5 += __shfl_xor(a5, 16); a5 += __shfl_xor(a5, 32);
    a6 += __shfl_xor(a6, 16); a6 += __shfl_xor(a6, 32);
    a7 += __shfl_xor(a7, 16); a7 += __shfl_xor(a7, 32);
    if (lane < 16) {
        float inv = 1.f / fmaxf(den, 1e-16f);
        float4 b0v = *(const float4*)&bias[ql * 8];
        float4 b1v = *(const float4*)&bias[ql * 8 + 4];
        float r0 = fmaxf(a0 * inv + b0v.x, 0.f);
        float r1 = fmaxf(a1 * inv + b0v.y, 0.f);
        float r2 = fmaxf(a2 * inv + b0v.z, 0.f);
        float r3 = fmaxf(a3 * inv + b0v.w, 0.f);
        float r4 = fmaxf(a4 * inv + b1v.x, 0.f);
        float r5 = fmaxf(a5 * inv + b1v.y, 0.f);
        float r6 = fmaxf(a6 * inv + b1v.z, 0.f);
        float r7 = fmaxf(a7 * inv + b1v.w, 0.f);
        *(uint4*)&actb[(size_t)node * HID + ql * 8] =
            make_uint4(pk2(r0, r1), pk2(r2, r3), pk2(r4, r5), pk2(r6, r7));
    }
}

// ---------------- Layer 1 GEMM: h1(bf16) = act(bf16) @ W1^T, fused alpha dots --
__global__ __launch_bounds__(128) void k_gemm1(
    const unsigned short* __restrict__ actb, const float* __restrict__ W1,
    const float* __restrict__ a_s, const float* __restrict__ a_d,
    unsigned short* __restrict__ h1b, float* __restrict__ as1, float* __restrict__ ad1) {
    __shared__ float w1l[NCLS * HID];
    __shared__ float av[NCLS], adv[NCLS];
    int t = threadIdx.x;
    #pragma unroll
    for (int i = 0; i < 10; ++i) {
        int j = t + 128 * i;
        ((float4*)w1l)[j] = ((const float4*)W1)[j];
    }
    if (t < NCLS) { av[t] = a_s[t]; adv[t] = a_d[t]; }
    __syncthreads();
    int n = blockIdx.x * 128 + t;
    if (n >= N_NODES) return;
    const uint4* ar = (const uint4*)(actb + (size_t)n * HID);   // 8 bf16 per uint4
    float acc[NCLS];
    #pragma unroll
    for (int c = 0; c < NCLS; ++c) acc[c] = 0.f;
    for (int k0 = 0; k0 < HID; k0 += 8) {
        uint4 v = ar[k0 >> 3];
        float x0 = blo(v.x), x1 = bhi(v.x), x2 = blo(v.y), x3 = bhi(v.y);
        float x4 = blo(v.z), x5 = bhi(v.z), x6 = blo(v.w), x7 = bhi(v.w);
        #pragma unroll
        for (int c = 0; c < NCLS; ++c) {
            const float* wr = &w1l[c * HID + k0];
            acc[c] += x0 * wr[0] + x1 * wr[1] + x2 * wr[2] + x3 * wr[3]
                    + x4 * wr[4] + x5 * wr[5] + x6 * wr[6] + x7 * wr[7];
        }
    }
    float ps = 0.f, pd = 0.f;
    #pragma unroll
    for (int c = 0; c < NCLS; ++c) { ps += acc[c] * av[c]; pd += acc[c] * adv[c]; }
    unsigned pk_[20];
    #pragma unroll
    for (int c = 0; c < 20; ++c) pk_[c] = pk2(acc[2 * c], acc[2 * c + 1]);
    #pragma unroll
    for (int i = 0; i < 5; ++i)
        *(uint4*)&h1b[(size_t)n * NCLS + i * 8] = make_uint4(pk_[4*i], pk_[4*i+1], pk_[4*i+2], pk_[4*i+3]);
    as1[n] = ps; ad1[n] = pd;
}

// ---------------- Aggregation layer 1 (bf16 h1, C=40): quarter-wave uint2 ------
__global__ __launch_bounds__(256) void k_agg1(
    const uint2* __restrict__ h1u, const float* __restrict__ as, const float* __restrict__ ad,
    const int* __restrict__ rp, const int* __restrict__ re, const int* __restrict__ csr,
    const float* __restrict__ bias, float* __restrict__ out) {
    __shared__ float sw_[4][64];
    __shared__ int   ss_[4][64];
    int wid = threadIdx.x >> 6, lane = threadIdx.x & 63;
    int q = lane >> 4, ql = lane & 15;
    int off10 = (ql < 10) ? ql : 0;   // lanes 10-15 of each group read col 0 (discarded)
    int node = blockIdx.x * 4 + wid;
    int start = rp[node], end = re[node];
    float ad_n = ad[node];
    float a0 = 0.f, a1 = 0.f, a2 = 0.f, a3 = 0.f, den = 0.f;
    for (int base = start; base < end; base += 64) {
        int mm = end - base; if (mm > 64) mm = 64;
        int s_l = 0; float w_l = 0.f;
        if (lane < mm) {
            s_l = csr[base + lane];
            float e = as[s_l] + ad_n;
            e = (e > 0.f) ? e : NEG * e;
            w_l = __expf(e);
            den += w_l;
        }
        ss_[wid][lane] = s_l;
        sw_[wid][lane] = w_l;
        for (int jj = 0; jj < mm; jj += 16) {
            int i0 = jj + q, i1 = i0 + 4, i2 = i0 + 8, i3 = i0 + 12;
            int   s0 = ss_[wid][i0], s1 = ss_[wid][i1], s2 = ss_[wid][i2], s3 = ss_[wid][i3];
            float w0 = sw_[wid][i0], w1 = sw_[wid][i1], w2 = sw_[wid][i2], w3 = sw_[wid][i3];
            uint2 u0 = h1u[(size_t)s0 * 10 + off10];
            uint2 u1 = h1u[(size_t)s1 * 10 + off10];
            uint2 u2 = h1u[(size_t)s2 * 10 + off10];
            uint2 u3 = h1u[(size_t)s3 * 10 + off10];
            a0 += w0 * blo(u0.x) + w1 * blo(u1.x) + w2 * blo(u2.x) + w3 * blo(u3.x);
            a1 += w0 * bhi(u0.x) + w1 * bhi(u1.x) + w2 * bhi(u2.x) + w3 * bhi(u3.x);
            a2 += w0 * blo(u0.y) + w1 * blo(u1.y) + w2 * blo(u2.y) + w3 * blo(u3.y);
            a3 += w0 * bhi(u0.y) + w1 * bhi(u1.y) + w2 * bhi(u2.y) + w3 * bhi(u3.y);
        }
    }
    #pragma unroll
    for (int off = 32; off; off >>= 1) den += __shfl_xor(den, off);
    a0 += __shfl_xor(a0, 16); a0 += __shfl_xor(a0, 32);
    a1 += __shfl_xor(a1, 16); a1 += __shfl_xor(a1, 32);
    a2 += __shfl_xor(a2, 16); a2 += __shfl_xor(a2, 32);
    a3 += __shfl_xor(a3, 16); a3 += __shfl_xor(a3, 32);
    if (lane < 10) {
        float inv = 1.f / fmaxf(den, 1e-16f);
        float4 b4 = *(const float4*)&bias[ql * 4];
        float4 r;
        r.x = a0 * inv + b4.x;
        r.y = a1 * inv + b4.y;
        r.z = a2 * inv + b4.z;
        r.w = a3 * inv + b4.w;
        *(float4*)&out[(size_t)node * NCLS + ql * 4] = r;
    }
}

extern "C" void kernel_launch(void* const* d_in, const int* in_sizes, int n_in,
                              void* d_out, int out_size, void* d_ws, size_t ws_size,
                              hipStream_t stream) {
    const float* x    = (const float*)d_in[0];
    const int*   ei   = (const int*)d_in[1];
    const float* W0   = (const float*)d_in[2];
    const float* a_s0 = (const float*)d_in[3];
    const float* a_d0 = (const float*)d_in[4];
    const float* b0   = (const float*)d_in[5];
    const float* W1   = (const float*)d_in[6];
    const float* a_s1 = (const float*)d_in[7];
    const float* a_d1 = (const float*)d_in[8];
    const float* b1   = (const float*)d_in[9];

    char* p = (char*)d_ws;
    auto alloc = [&](size_t bytes) { void* q = p; p += (bytes + 255) & ~size_t(255); return q; };
    unsigned short* h0b  = (unsigned short*)alloc((size_t)N_NODES * HID * 2);  // 12.8MB bf16
    unsigned int*   buf  = (unsigned int*)alloc((size_t)NBUCK * CAP * 4);      // 8.0MB (no aliasing: gemm0 concurrent)
    int*   csr    = (int*)alloc((size_t)NBUCK * CAP * 4);                      // 8.0MB bucket-major
    unsigned short* h1b  = (unsigned short*)alloc(((size_t)N_NODES * NCLS + 32) * 2);
    unsigned short* actb = (unsigned short*)alloc((size_t)N_NODES * HID * 2);  // bf16
    float* as0    = (float*)alloc((size_t)N_NODES * 4);
    float* ad0    = (float*)alloc((size_t)N_NODES * 4);
    float* as1    = (float*)alloc((size_t)N_NODES * 4);
    float* ad1    = (float*)alloc((size_t)N_NODES * 4);
    int*   rp     = (int*)alloc((size_t)N_NODES * 4);
    int*   re     = (int*)alloc((size_t)N_NODES * 4);
    int*   cursor = (int*)alloc((size_t)NBUCK * 4);

    hipMemsetAsync(cursor, 0, (size_t)NBUCK * 4, stream);
    k_fused<<<SCATB + GEMMB, 256, 0, stream>>>(ei, cursor, buf, x, W0, a_s0, a_d0, h0b, as0, ad0);
    k_bucket_build<<<NBUCK, 512, 0, stream>>>(buf, cursor, rp, re, csr);
    k_agg0<<<N_NODES / 4, 256, 0, stream>>>((const uint4*)h0b, as0, ad0, rp, re, csr, b0, actb);
    k_gemm1<<<(N_NODES + 127) / 128, 128, 0, stream>>>(actb, W1, a_s1, a_d1, h1b, as1, ad1);
    k_agg1<<<N_NODES / 4, 256, 0, stream>>>((const uint2*)h1b, as1, ad1, rp, re, csr, b1, (float*)d_out);
}